// Round 15
// baseline (254.189 us; speedup 1.0000x reference)
//
#include <hip/hip_runtime.h>
#include <hip/hip_bf16.h>
#include <math.h>

#define BB 8
#define HH 512
#define WW 512
#define NPIX (BB * HH * WW)        // 2097152
#define HWPIX (HH * WW)            // 262144 = 2^18
#define PBUD 1048576               // P
#define RAD 7                      // 15//2
#define NB (NPIX / 256)            // 8192 rank blocks of 256 pixels
#define NMLP (NPIX / 128)          // 16384 MLP tiles of 128 pixels

typedef __attribute__((ext_vector_type(4))) float f32x4;
typedef __attribute__((ext_vector_type(8))) short short8;
typedef __attribute__((ext_vector_type(4))) unsigned int u32x4;

__device__ __forceinline__ unsigned short f2bf(float f) {
    unsigned int u = __float_as_uint(f);
    unsigned int r = (u + 0x7fffu + ((u >> 16) & 1u)) >> 16;   // RNE
    return (unsigned short)r;
}

__device__ __forceinline__ unsigned int pkbf(float a, float b) {
    __hip_bfloat162 h = __float22bfloat162_rn(make_float2(a, b));
    return *(unsigned int*)&h;
}

// ---- K0: W2 B-fragments (verified r5-r12) ------------------------------------
__global__ void k_prep_w2(const float* __restrict__ w2, unsigned short* __restrict__ w2f) {
    int i = blockIdx.x * 256 + threadIdx.x;   // 16384 threads
    int e  = i & 7;
    int l  = (i >> 3) & 63;
    int ks = (i >> 9) & 3;
    int jc = i >> 11;
    int j = jc * 16 + (l & 15);
    int k = ks * 32 + ((l >> 4) & 3) * 8 + e;
    w2f[i] = f2bf(w2[k * 128 + j]);
}

// ---------------- K1: mask + horizontal dilate --------------------------------
__global__ void k_rowdil(const float* __restrict__ lr, unsigned char* __restrict__ rowdil) {
    int p = blockIdx.x * 256 + threadIdx.x;
    int w = p & (WW - 1);
    int row0 = p - w;
    int lo = w - RAD; if (lo < 0) lo = 0;
    int hi = w + RAD; if (hi > WW - 1) hi = WW - 1;
    unsigned char any = 0;
    for (int x = lo; x <= hi; ++x) {
        float v = lr[row0 + x];
        any |= (unsigned char)(v > 0.01f && v < 0.99f);
    }
    rowdil[p] = any;
}

// ------- K2: vertical dilate + per-256-block count + intra-block rank byte ----
__global__ void k_coldil(const unsigned char* __restrict__ rowdil,
                         unsigned char* __restrict__ dm,
                         unsigned char* __restrict__ rankb,
                         int* __restrict__ gsum) {
    int p = blockIdx.x * 256 + threadIdx.x;
    int h = (p >> 9) & (HH - 1);
    int lo = h - RAD; if (lo < 0) lo = 0;
    int hi = h + RAD; if (hi > HH - 1) hi = HH - 1;
    lo -= h; hi -= h;
    unsigned char any = 0;
    for (int d = lo; d <= hi; ++d) any |= rowdil[p + d * WW];
    dm[p] = any;

    unsigned long long bal = __ballot(any != 0);
    __shared__ int wsum[4];
    int lane = threadIdx.x & 63;
    int wid  = threadIdx.x >> 6;
    if (lane == 0) wsum[wid] = __popcll(bal);
    __syncthreads();
    int pre = __popcll(bal & ((1ull << lane) - 1ull));
    int woff = 0;
    for (int i = 0; i < wid; ++i) woff += wsum[i];
    rankb[p] = (unsigned char)(woff + pre);
    if (threadIdx.x == 0) gsum[blockIdx.x] = wsum[0] + wsum[1] + wsum[2] + wsum[3];
}

// ---------------- K3: exclusive scan of 8192 block counts (one block) ---------
__global__ void k_scan(const int* __restrict__ gsum, int* __restrict__ goff) {
    __shared__ int tsum[1024];
    int t = threadIdx.x;
    int base = t * 8;
    int v[8];
    int s = 0;
#pragma unroll
    for (int i = 0; i < 8; ++i) { v[i] = gsum[base + i]; s += v[i]; }
    tsum[t] = s;
    __syncthreads();
    for (int off = 1; off < 1024; off <<= 1) {
        int x = tsum[t];
        int y = (t >= off) ? tsum[t - off] : 0;
        __syncthreads();
        tsum[t] = x + y;
        __syncthreads();
    }
    int run = (t == 0) ? 0 : tsum[t - 1];
#pragma unroll
    for (int i = 0; i < 8; ++i) { goff[base + i] = run; run += v[i]; }
}

// ---------------- K4: r12 kernel, templated for phase ablation ----------------
// V=0 full (r12 verbatim) | V=1 phase0+1 only | V=2 phase0+2 only | V=3 phase0+copy
// Ablation dispatches (V3,V1,V2) may scribble on out; the final V0 dispatch
// rewrites EVERY pixel, so the end state is correct and replay-deterministic.
template<int V>
__global__ __launch_bounds__(256, 4)
void k_mlp_t(const float* __restrict__ image, const float* __restrict__ lr,
             const float* __restrict__ w1, const float* __restrict__ b1,
             const unsigned short* __restrict__ w2f, const float* __restrict__ b2,
             const float* __restrict__ w3, const float* __restrict__ b3,
             const unsigned char* __restrict__ dm, const unsigned char* __restrict__ rankb,
             const int* __restrict__ goff, float* __restrict__ out) {
    __shared__ __align__(16) char lds[32768];
    __shared__ int s_any;
    int g  = blockIdx.x;
    int p0 = g * 128;
    int t  = threadIdx.x;

    // ---- phase 0: any selected pixel in this 128-px tile? ----
    if (t == 0) s_any = 0;
    __syncthreads();
    if (t < 128) {
        int p = p0 + t;
        if (dm[p] && (goff[p >> 8] + (int)rankb[p] < PBUD)) s_any = 1;
    }
    __syncthreads();
    if (!s_any) {
        if (t < 128) out[p0 + t] = lr[p0 + t];
        return;
    }

    if constexpr (V == 3) {               // selection floor: copy and leave
        if (t < 128) out[p0 + t] = lr[p0 + t];
        return;
    }

    // ---- phase 1: layer 1 (4 -> 128) -> bf16 H1 in LDS (swizzled) ----
    if constexpr (V == 0 || V == 1) {
        int px = t & 127;
        int jh = __builtin_amdgcn_readfirstlane(t >> 7);   // 0 or 1
        int p  = p0 + px;
        float lrv = lr[p];
        size_t bimg = (size_t)(p >> 18) * 3 * HWPIX + (p & (HWPIX - 1));
        float x0 = image[bimg];
        float x1 = image[bimg + HWPIX];
        float x2 = image[bimg + 2 * HWPIX];
        float x3 = 2.0f * lrv - 1.0f;
#pragma unroll
        for (int jc8 = 0; jc8 < 8; ++jc8) {
            int jc = jh * 8 + jc8;
            float h[8];
#pragma unroll
            for (int e = 0; e < 8; ++e) {
                int j = jc * 8 + e;
                float a = b1[j];
                a = fmaf(x0, w1[j], a);
                a = fmaf(x1, w1[128 + j], a);
                a = fmaf(x2, w1[256 + j], a);
                a = fmaf(x3, w1[384 + j], a);
                h[e] = fmaxf(a, 0.0f);
            }
            u32x4 pk = { pkbf(h[0], h[1]), pkbf(h[2], h[3]),
                         pkbf(h[4], h[5]), pkbf(h[6], h[7]) };
            if constexpr (V == 1) {        // keepalive against DCE (rule #17)
                asm volatile("" :: "v"(pk[0]), "v"(pk[3]));
            }
            int a = (((px << 8) | (jc << 4))) ^ ((px & 15) << 4);
            *(u32x4*)(lds + a) = pk;
        }
        if constexpr (V == 1) {
            if (t < 128) out[p] = lrv;     // a store so the block has output work
            return;
        }
    }
    if constexpr (V == 0) __syncthreads();
    // V == 2 falls through: phase 2 reads whatever LDS holds (garbage ok)

    // ---- phase 2: wave w computes rows [w*32, w*32+32) x all 128 cols ----
    int w    = t >> 6;
    int l    = t & 63;
    int lr16 = l & 15;
    int lh   = l >> 4;
    int rowbase = w * 32;

    short8 af[2][4];
#pragma unroll
    for (int ks = 0; ks < 4; ++ks) {
#pragma unroll
        for (int mt = 0; mt < 2; ++mt) {
            int row = rowbase + mt * 16 + lr16;
            int a = (((row << 8) | (ks << 6) | (lh << 4))) ^ ((row & 15) << 4);
            af[mt][ks] = *(const short8*)(lds + a);
        }
    }

    float b2v[8], w3v[8];
#pragma unroll
    for (int jc = 0; jc < 8; ++jc) {
        int col = jc * 16 + lr16;
        b2v[jc] = b2[col];
        w3v[jc] = w3[col];
    }
    float b3v = b3[0];

    f32x4 acc[2][8];
#pragma unroll
    for (int mt = 0; mt < 2; ++mt)
#pragma unroll
        for (int jc = 0; jc < 8; ++jc)
            acc[mt][jc] = (f32x4){b2v[jc], b2v[jc], b2v[jc], b2v[jc]};

    const short8* wf = (const short8*)w2f;
#pragma unroll
    for (int jc = 0; jc < 8; ++jc) {
        short8 bf[4];
#pragma unroll
        for (int ks = 0; ks < 4; ++ks) bf[ks] = wf[(jc * 4 + ks) * 64 + l];
#pragma unroll
        for (int ks = 0; ks < 4; ++ks) {
            acc[0][jc] = __builtin_amdgcn_mfma_f32_16x16x32_bf16(af[0][ks], bf[ks], acc[0][jc], 0, 0, 0);
            acc[1][jc] = __builtin_amdgcn_mfma_f32_16x16x32_bf16(af[1][ks], bf[ks], acc[1][jc], 0, 0, 0);
        }
    }

    // ---- epilogue: relu + dot(w3) reduce + sigmoid + select ----
#pragma unroll
    for (int mt = 0; mt < 2; ++mt) {
#pragma unroll
        for (int r = 0; r < 4; ++r) {
            int row = rowbase + mt * 16 + lh * 4 + r;
            float part = 0.f;
#pragma unroll
            for (int jc = 0; jc < 8; ++jc)
                part += fmaxf(acc[mt][jc][r], 0.f) * w3v[jc];
            part += __shfl_xor(part, 1);
            part += __shfl_xor(part, 2);
            part += __shfl_xor(part, 4);
            part += __shfl_xor(part, 8);
            if (lr16 == 0) {
                int p = p0 + row;
                float lrv = lr[p];
                bool s = dm[p] && (goff[p >> 8] + (int)rankb[p] < PBUD);
                float logit = b3v + part;
                out[p] = s ? (1.0f / (1.0f + __expf(-logit))) : lrv;
            }
        }
    }
}

// ---------------- launcher ----------------------------------------------------
extern "C" void kernel_launch(void* const* d_in, const int* in_sizes, int n_in,
                              void* d_out, int out_size, void* d_ws, size_t ws_size,
                              hipStream_t stream) {
    const float* image = (const float*)d_in[0];
    const float* lr    = (const float*)d_in[1];
    const float* w1    = (const float*)d_in[2];
    const float* b1    = (const float*)d_in[3];
    const float* w2    = (const float*)d_in[4];
    const float* b2    = (const float*)d_in[5];
    const float* w3    = (const float*)d_in[6];
    const float* b3    = (const float*)d_in[7];
    float* out = (float*)d_out;

    char* ws = (char*)d_ws;
    unsigned char* rowdil = (unsigned char*)ws;                         // NPIX
    unsigned char* dm     = (unsigned char*)(ws + (size_t)NPIX);        // NPIX
    unsigned char* rankb  = (unsigned char*)(ws + 2 * (size_t)NPIX);    // NPIX
    int* gsum             = (int*)(ws + 3 * (size_t)NPIX);              // NB
    int* goff             = (int*)(ws + 3 * (size_t)NPIX + NB * 4);     // NB
    unsigned short* w2f   = (unsigned short*)(ws + 3 * (size_t)NPIX + 2 * NB * 4); // 16384 bf16

    k_prep_w2<<<64, 256, 0, stream>>>(w2, w2f);
    k_rowdil <<<NPIX / 256, 256, 0, stream>>>(lr, rowdil);
    k_coldil <<<NB, 256, 0, stream>>>(rowdil, dm, rankb, gsum);
    k_scan   <<<1, 1024, 0, stream>>>(gsum, goff);

    // Ablation probes (results overwritten by the final full dispatch):
    k_mlp_t<3><<<NMLP, 256, 0, stream>>>(image, lr, w1, b1, w2f, b2, w3, b3, dm, rankb, goff, out);
    k_mlp_t<1><<<NMLP, 256, 0, stream>>>(image, lr, w1, b1, w2f, b2, w3, b3, dm, rankb, goff, out);
    k_mlp_t<2><<<NMLP, 256, 0, stream>>>(image, lr, w1, b1, w2f, b2, w3, b3, dm, rankb, goff, out);
    // Authoritative full kernel — writes every output pixel:
    k_mlp_t<0><<<NMLP, 256, 0, stream>>>(image, lr, w1, b1, w2f, b2, w3, b3, dm, rankb, goff, out);
}

// Round 16
// 134.586 us; speedup vs baseline: 1.8887x; 1.8887x over previous
//
#include <hip/hip_runtime.h>
#include <hip/hip_bf16.h>
#include <math.h>

#define BB 8
#define HH 512
#define WW 512
#define NPIX (BB * HH * WW)        // 2097152
#define HWPIX (HH * WW)            // 262144 = 2^18
#define PBUD 1048576               // P
#define RAD 7                      // 15//2
#define NB (NPIX / 256)            // 8192 rank blocks of 256 pixels
#define NMLP (NPIX / 128)          // 16384 MLP tiles of 128 pixels

typedef __attribute__((ext_vector_type(4))) float f32x4;
typedef __attribute__((ext_vector_type(8))) short short8;
typedef __attribute__((ext_vector_type(4))) unsigned int u32x4;

__device__ __forceinline__ unsigned short f2bf(float f) {
    unsigned int u = __float_as_uint(f);
    unsigned int r = (u + 0x7fffu + ((u >> 16) & 1u)) >> 16;   // RNE
    return (unsigned short)r;
}

__device__ __forceinline__ unsigned int pkbf(float a, float b) {
    __hip_bfloat162 h = __float22bfloat162_rn(make_float2(a, b));
    return *(unsigned int*)&h;
}

// ---- K0: W2 B-fragments (verified r5-r15) ------------------------------------
__global__ void k_prep_w2(const float* __restrict__ w2, unsigned short* __restrict__ w2f) {
    int i = blockIdx.x * 256 + threadIdx.x;   // 16384 threads
    int e  = i & 7;
    int l  = (i >> 3) & 63;
    int ks = (i >> 9) & 3;
    int jc = i >> 11;
    int j = jc * 16 + (l & 15);
    int k = ks * 32 + ((l >> 4) & 3) * 8 + e;
    w2f[i] = f2bf(w2[k * 128 + j]);
}

// ---------------- K1: mask + horizontal dilate --------------------------------
__global__ void k_rowdil(const float* __restrict__ lr, unsigned char* __restrict__ rowdil) {
    int p = blockIdx.x * 256 + threadIdx.x;
    int w = p & (WW - 1);
    int row0 = p - w;
    int lo = w - RAD; if (lo < 0) lo = 0;
    int hi = w + RAD; if (hi > WW - 1) hi = WW - 1;
    unsigned char any = 0;
    for (int x = lo; x <= hi; ++x) {
        float v = lr[row0 + x];
        any |= (unsigned char)(v > 0.01f && v < 0.99f);
    }
    rowdil[p] = any;
}

// ------- K2: vertical dilate + per-256-block count + intra-block rank byte ----
__global__ void k_coldil(const unsigned char* __restrict__ rowdil,
                         unsigned char* __restrict__ dm,
                         unsigned char* __restrict__ rankb,
                         int* __restrict__ gsum) {
    int p = blockIdx.x * 256 + threadIdx.x;
    int h = (p >> 9) & (HH - 1);
    int lo = h - RAD; if (lo < 0) lo = 0;
    int hi = h + RAD; if (hi > HH - 1) hi = HH - 1;
    lo -= h; hi -= h;
    unsigned char any = 0;
    for (int d = lo; d <= hi; ++d) any |= rowdil[p + d * WW];
    dm[p] = any;

    unsigned long long bal = __ballot(any != 0);
    __shared__ int wsum[4];
    int lane = threadIdx.x & 63;
    int wid  = threadIdx.x >> 6;
    if (lane == 0) wsum[wid] = __popcll(bal);
    __syncthreads();
    int pre = __popcll(bal & ((1ull << lane) - 1ull));
    int woff = 0;
    for (int i = 0; i < wid; ++i) woff += wsum[i];
    rankb[p] = (unsigned char)(woff + pre);
    if (threadIdx.x == 0) gsum[blockIdx.x] = wsum[0] + wsum[1] + wsum[2] + wsum[3];
}

// ---------------- K3: exclusive scan of 8192 block counts (one block) ---------
__global__ void k_scan(const int* __restrict__ gsum, int* __restrict__ goff) {
    __shared__ int tsum[1024];
    int t = threadIdx.x;
    int base = t * 8;
    int v[8];
    int s = 0;
#pragma unroll
    for (int i = 0; i < 8; ++i) { v[i] = gsum[base + i]; s += v[i]; }
    tsum[t] = s;
    __syncthreads();
    for (int off = 1; off < 1024; off <<= 1) {
        int x = tsum[t];
        int y = (t >= off) ? tsum[t - off] : 0;
        __syncthreads();
        tsum[t] = x + y;
        __syncthreads();
    }
    int run = (t == 0) ? 0 : tsum[t - 1];
#pragma unroll
    for (int i = 0; i < 8; ++i) { goff[base + i] = run; run += v[i]; }
}

// ---------------- K4: r12 kernel + double-buffered w2f prefetch ---------------
// Diagnosis (r15 ablation): phases serialize; phase 2 is load-latency-bound
// (VGPR=60 -> compiler issued w2f loads just-in-time, 8 exposed L1 latencies).
// Fix: manual 1-deep double-buffer bfA/bfB across the jc loop; jc=0 loads
// issued BEFORE the barrier so they drain during it. w3v moved to epilogue.
__global__ __launch_bounds__(256, 4)
void k_mlp(const float* __restrict__ image, const float* __restrict__ lr,
           const float* __restrict__ w1, const float* __restrict__ b1,
           const unsigned short* __restrict__ w2f, const float* __restrict__ b2,
           const float* __restrict__ w3, const float* __restrict__ b3,
           const unsigned char* __restrict__ dm, const unsigned char* __restrict__ rankb,
           const int* __restrict__ goff, float* __restrict__ out) {
    __shared__ __align__(16) char lds[32768];
    __shared__ int s_any;
    int g  = blockIdx.x;
    int p0 = g * 128;
    int t  = threadIdx.x;

    // ---- phase 0: any selected pixel in this 128-px tile? ----
    if (t == 0) s_any = 0;
    __syncthreads();
    if (t < 128) {
        int p = p0 + t;
        if (dm[p] && (goff[p >> 8] + (int)rankb[p] < PBUD)) s_any = 1;
    }
    __syncthreads();
    if (!s_any) {
        if (t < 128) out[p0 + t] = lr[p0 + t];
        return;
    }

    int l = t & 63;
    const short8* wf = (const short8*)w2f;
    // jc=0 B-fragments: issue now, consumed after the barrier (latency hidden)
    short8 bfA0 = wf[(0 * 4 + 0) * 64 + l];
    short8 bfA1 = wf[(0 * 4 + 1) * 64 + l];
    short8 bfA2 = wf[(0 * 4 + 2) * 64 + l];
    short8 bfA3 = wf[(0 * 4 + 3) * 64 + l];

    // ---- phase 1: layer 1 (4 -> 128) -> bf16 H1 in LDS (swizzled) ----
    {
        int px = t & 127;
        int jh = __builtin_amdgcn_readfirstlane(t >> 7);   // 0 or 1
        int p  = p0 + px;
        float lrv = lr[p];
        size_t bimg = (size_t)(p >> 18) * 3 * HWPIX + (p & (HWPIX - 1));
        float x0 = image[bimg];
        float x1 = image[bimg + HWPIX];
        float x2 = image[bimg + 2 * HWPIX];
        float x3 = 2.0f * lrv - 1.0f;
#pragma unroll
        for (int jc8 = 0; jc8 < 8; ++jc8) {
            int jc = jh * 8 + jc8;
            float h[8];
#pragma unroll
            for (int e = 0; e < 8; ++e) {
                int j = jc * 8 + e;        // SGPR-computable -> s_load
                float a = b1[j];
                a = fmaf(x0, w1[j], a);
                a = fmaf(x1, w1[128 + j], a);
                a = fmaf(x2, w1[256 + j], a);
                a = fmaf(x3, w1[384 + j], a);
                h[e] = fmaxf(a, 0.0f);
            }
            u32x4 pk = { pkbf(h[0], h[1]), pkbf(h[2], h[3]),
                         pkbf(h[4], h[5]), pkbf(h[6], h[7]) };
            int a = (((px << 8) | (jc << 4))) ^ ((px & 15) << 4);
            *(u32x4*)(lds + a) = pk;
        }
    }
    __syncthreads();

    // ---- phase 2: wave w computes rows [w*32, w*32+32) x all 128 cols ----
    int w    = t >> 6;
    int lr16 = l & 15;
    int lh   = l >> 4;
    int rowbase = w * 32;

    short8 af[2][4];
#pragma unroll
    for (int ks = 0; ks < 4; ++ks) {
#pragma unroll
        for (int mt = 0; mt < 2; ++mt) {
            int row = rowbase + mt * 16 + lr16;
            int a = (((row << 8) | (ks << 6) | (lh << 4))) ^ ((row & 15) << 4);
            af[mt][ks] = *(const short8*)(lds + a);
        }
    }

    f32x4 acc[2][8];
#pragma unroll
    for (int jc = 0; jc < 8; ++jc) {
        float b2v = b2[jc * 16 + lr16];
#pragma unroll
        for (int mt = 0; mt < 2; ++mt)
            acc[mt][jc] = (f32x4){b2v, b2v, b2v, b2v};
    }

    // software-pipelined jc loop: prefetch jc+1 while MFMAing jc
#pragma unroll
    for (int jc = 0; jc < 8; ++jc) {
        short8 bfB0, bfB1, bfB2, bfB3;
        if (jc < 7) {
            bfB0 = wf[((jc + 1) * 4 + 0) * 64 + l];
            bfB1 = wf[((jc + 1) * 4 + 1) * 64 + l];
            bfB2 = wf[((jc + 1) * 4 + 2) * 64 + l];
            bfB3 = wf[((jc + 1) * 4 + 3) * 64 + l];
        }
        acc[0][jc] = __builtin_amdgcn_mfma_f32_16x16x32_bf16(af[0][0], bfA0, acc[0][jc], 0, 0, 0);
        acc[1][jc] = __builtin_amdgcn_mfma_f32_16x16x32_bf16(af[1][0], bfA0, acc[1][jc], 0, 0, 0);
        acc[0][jc] = __builtin_amdgcn_mfma_f32_16x16x32_bf16(af[0][1], bfA1, acc[0][jc], 0, 0, 0);
        acc[1][jc] = __builtin_amdgcn_mfma_f32_16x16x32_bf16(af[1][1], bfA1, acc[1][jc], 0, 0, 0);
        acc[0][jc] = __builtin_amdgcn_mfma_f32_16x16x32_bf16(af[0][2], bfA2, acc[0][jc], 0, 0, 0);
        acc[1][jc] = __builtin_amdgcn_mfma_f32_16x16x32_bf16(af[1][2], bfA2, acc[1][jc], 0, 0, 0);
        acc[0][jc] = __builtin_amdgcn_mfma_f32_16x16x32_bf16(af[0][3], bfA3, acc[0][jc], 0, 0, 0);
        acc[1][jc] = __builtin_amdgcn_mfma_f32_16x16x32_bf16(af[1][3], bfA3, acc[1][jc], 0, 0, 0);
        if (jc < 7) { bfA0 = bfB0; bfA1 = bfB1; bfA2 = bfB2; bfA3 = bfB3; }
    }

    // ---- epilogue: relu + dot(w3) reduce + sigmoid + select ----
    float w3v[8];
#pragma unroll
    for (int jc = 0; jc < 8; ++jc) w3v[jc] = w3[jc * 16 + lr16];
    float b3v = b3[0];

#pragma unroll
    for (int mt = 0; mt < 2; ++mt) {
#pragma unroll
        for (int r = 0; r < 4; ++r) {
            int row = rowbase + mt * 16 + lh * 4 + r;   // C/D: row = (lane>>4)*4 + reg
            float part = 0.f;
#pragma unroll
            for (int jc = 0; jc < 8; ++jc)
                part += fmaxf(acc[mt][jc][r], 0.f) * w3v[jc];
            part += __shfl_xor(part, 1);
            part += __shfl_xor(part, 2);
            part += __shfl_xor(part, 4);
            part += __shfl_xor(part, 8);
            if (lr16 == 0) {
                int p = p0 + row;
                float lrv = lr[p];
                bool s = dm[p] && (goff[p >> 8] + (int)rankb[p] < PBUD);
                float logit = b3v + part;
                out[p] = s ? (1.0f / (1.0f + __expf(-logit))) : lrv;
            }
        }
    }
}

// ---------------- launcher ----------------------------------------------------
extern "C" void kernel_launch(void* const* d_in, const int* in_sizes, int n_in,
                              void* d_out, int out_size, void* d_ws, size_t ws_size,
                              hipStream_t stream) {
    const float* image = (const float*)d_in[0];
    const float* lr    = (const float*)d_in[1];
    const float* w1    = (const float*)d_in[2];
    const float* b1    = (const float*)d_in[3];
    const float* w2    = (const float*)d_in[4];
    const float* b2    = (const float*)d_in[5];
    const float* w3    = (const float*)d_in[6];
    const float* b3    = (const float*)d_in[7];
    float* out = (float*)d_out;

    char* ws = (char*)d_ws;
    unsigned char* rowdil = (unsigned char*)ws;                         // NPIX
    unsigned char* dm     = (unsigned char*)(ws + (size_t)NPIX);        // NPIX
    unsigned char* rankb  = (unsigned char*)(ws + 2 * (size_t)NPIX);    // NPIX
    int* gsum             = (int*)(ws + 3 * (size_t)NPIX);              // NB
    int* goff             = (int*)(ws + 3 * (size_t)NPIX + NB * 4);     // NB
    unsigned short* w2f   = (unsigned short*)(ws + 3 * (size_t)NPIX + 2 * NB * 4); // 16384 bf16

    k_prep_w2<<<64, 256, 0, stream>>>(w2, w2f);
    k_rowdil <<<NPIX / 256, 256, 0, stream>>>(lr, rowdil);
    k_coldil <<<NB, 256, 0, stream>>>(rowdil, dm, rankb, gsum);
    k_scan   <<<1, 1024, 0, stream>>>(gsum, goff);
    k_mlp    <<<NMLP, 256, 0, stream>>>(image, lr, w1, b1, w2f, b2, w3, b3,
                                        dm, rankb, goff, out);
}

// Round 17
// 132.331 us; speedup vs baseline: 1.9209x; 1.0170x over previous
//
#include <hip/hip_runtime.h>
#include <hip/hip_bf16.h>
#include <math.h>

#define BB 8
#define HH 512
#define WW 512
#define NPIX (BB * HH * WW)        // 2097152
#define HWPIX (HH * WW)            // 262144 = 2^18
#define PBUD 1048576               // P
#define RAD 7                      // 15//2
#define NB (NPIX / 256)            // 8192 rank blocks of 256 pixels
#define NMLP (NPIX / 128)          // 16384 MLP tiles of 128 pixels

typedef __attribute__((ext_vector_type(4))) float f32x4;
typedef __attribute__((ext_vector_type(8))) short short8;
typedef __attribute__((ext_vector_type(4))) unsigned int u32x4;

__device__ __forceinline__ unsigned short f2bf(float f) {
    unsigned int u = __float_as_uint(f);
    unsigned int r = (u + 0x7fffu + ((u >> 16) & 1u)) >> 16;   // RNE
    return (unsigned short)r;
}

__device__ __forceinline__ unsigned int pkbf(float a, float b) {
    __hip_bfloat162 h = __float22bfloat162_rn(make_float2(a, b));
    return *(unsigned int*)&h;
}

// ---- K0: W2 B-fragments (verified r5-r16) ------------------------------------
__global__ void k_prep_w2(const float* __restrict__ w2, unsigned short* __restrict__ w2f) {
    int i = blockIdx.x * 256 + threadIdx.x;   // 16384 threads
    int e  = i & 7;
    int l  = (i >> 3) & 63;
    int ks = (i >> 9) & 3;
    int jc = i >> 11;
    int j = jc * 16 + (l & 15);
    int k = ks * 32 + ((l >> 4) & 3) * 8 + e;
    w2f[i] = f2bf(w2[k * 128 + j]);
}

// ---------------- K1: mask + horizontal dilate --------------------------------
__global__ void k_rowdil(const float* __restrict__ lr, unsigned char* __restrict__ rowdil) {
    int p = blockIdx.x * 256 + threadIdx.x;
    int w = p & (WW - 1);
    int row0 = p - w;
    int lo = w - RAD; if (lo < 0) lo = 0;
    int hi = w + RAD; if (hi > WW - 1) hi = WW - 1;
    unsigned char any = 0;
    for (int x = lo; x <= hi; ++x) {
        float v = lr[row0 + x];
        any |= (unsigned char)(v > 0.01f && v < 0.99f);
    }
    rowdil[p] = any;
}

// ------- K2: vertical dilate + per-256-block count + intra-block rank byte ----
__global__ void k_coldil(const unsigned char* __restrict__ rowdil,
                         unsigned char* __restrict__ dm,
                         unsigned char* __restrict__ rankb,
                         int* __restrict__ gsum) {
    int p = blockIdx.x * 256 + threadIdx.x;
    int h = (p >> 9) & (HH - 1);
    int lo = h - RAD; if (lo < 0) lo = 0;
    int hi = h + RAD; if (hi > HH - 1) hi = HH - 1;
    lo -= h; hi -= h;
    unsigned char any = 0;
    for (int d = lo; d <= hi; ++d) any |= rowdil[p + d * WW];
    dm[p] = any;

    unsigned long long bal = __ballot(any != 0);
    __shared__ int wsum[4];
    int lane = threadIdx.x & 63;
    int wid  = threadIdx.x >> 6;
    if (lane == 0) wsum[wid] = __popcll(bal);
    __syncthreads();
    int pre = __popcll(bal & ((1ull << lane) - 1ull));
    int woff = 0;
    for (int i = 0; i < wid; ++i) woff += wsum[i];
    rankb[p] = (unsigned char)(woff + pre);
    if (threadIdx.x == 0) gsum[blockIdx.x] = wsum[0] + wsum[1] + wsum[2] + wsum[3];
}

// ---------------- K3: exclusive scan of 8192 block counts (one block) ---------
__global__ void k_scan(const int* __restrict__ gsum, int* __restrict__ goff) {
    __shared__ int tsum[1024];
    int t = threadIdx.x;
    int base = t * 8;
    int v[8];
    int s = 0;
#pragma unroll
    for (int i = 0; i < 8; ++i) { v[i] = gsum[base + i]; s += v[i]; }
    tsum[t] = s;
    __syncthreads();
    for (int off = 1; off < 1024; off <<= 1) {
        int x = tsum[t];
        int y = (t >= off) ? tsum[t - off] : 0;
        __syncthreads();
        tsum[t] = x + y;
        __syncthreads();
    }
    int run = (t == 0) ? 0 : tsum[t - 1];
#pragma unroll
    for (int i = 0; i < 8; ++i) { goff[base + i] = run; run += v[i]; }
}

// ---------------- K4: j-partitioned phase 2 -----------------------------------
// r15 ablation + arithmetic: phase 2's ~50us marginal = L1 service time of
// every wave reading ALL 32KB of w2f (32 x b128 x 16 lines x 16 cyc).
// Fix: wave w owns j-cols [w*32,(w+1)*32) for ALL 128 px -> 8KB w2f/wave (4x
// less L1 traffic). af now 32 ds_reads/wave (LDS is cheap). Per-mt fused
// epilogue -> PART[4][128] in LDS, one extra barrier, 128 threads combine.
// sel/lrv register-carried from phase 0 (no epilogue global reloads).
__global__ __launch_bounds__(256, 4)
void k_mlp(const float* __restrict__ image, const float* __restrict__ lr,
           const float* __restrict__ w1, const float* __restrict__ b1,
           const unsigned short* __restrict__ w2f, const float* __restrict__ b2,
           const float* __restrict__ w3, const float* __restrict__ b3,
           const unsigned char* __restrict__ dm, const unsigned char* __restrict__ rankb,
           const int* __restrict__ goff, float* __restrict__ out) {
    __shared__ __align__(16) char lds[32768];
    __shared__ float part_l[4][128];
    __shared__ int s_any;
    int g  = blockIdx.x;
    int p0 = g * 128;
    int t  = threadIdx.x;
    int px = t & 127;
    int p  = p0 + px;

    // ---- phase 0: selection (all threads; waves 2,3 duplicate 0,1) ----
    if (t == 0) s_any = 0;
    __syncthreads();
    float lrv = lr[p];
    bool  sel = dm[p] && (goff[p >> 8] + (int)rankb[p] < PBUD);
    if (sel) s_any = 1;
    __syncthreads();
    if (!s_any) {
        if (t < 128) out[p] = lrv;
        return;
    }

    int w    = t >> 6;
    int l    = t & 63;
    int lr16 = l & 15;
    int lh   = l >> 4;

    // this wave's B-fragments (jc = 2w, 2w+1): 8 KB/wave, issued early
    const short8* wf = (const short8*)w2f;
    short8 bf[2][4];
#pragma unroll
    for (int jj = 0; jj < 2; ++jj)
#pragma unroll
        for (int ks = 0; ks < 4; ++ks)
            bf[jj][ks] = wf[((2 * w + jj) * 4 + ks) * 64 + l];
    float b2v[2], w3v[2];
#pragma unroll
    for (int jj = 0; jj < 2; ++jj) {
        b2v[jj] = b2[(2 * w + jj) * 16 + lr16];
        w3v[jj] = w3[(2 * w + jj) * 16 + lr16];
    }
    float b3v = b3[0];

    // ---- phase 1: layer 1 (4 -> 128) -> bf16 H1 in LDS (r12 verbatim) ----
    {
        int jh = __builtin_amdgcn_readfirstlane(t >> 7);   // 0 or 1 -> s_load w1/b1
        size_t bimg = (size_t)(p >> 18) * 3 * HWPIX + (p & (HWPIX - 1));
        float x0 = image[bimg];
        float x1 = image[bimg + HWPIX];
        float x2 = image[bimg + 2 * HWPIX];
        float x3 = 2.0f * lrv - 1.0f;
#pragma unroll
        for (int jc8 = 0; jc8 < 8; ++jc8) {
            int jc = jh * 8 + jc8;
            float h[8];
#pragma unroll
            for (int e = 0; e < 8; ++e) {
                int j = jc * 8 + e;
                float a = b1[j];
                a = fmaf(x0, w1[j], a);
                a = fmaf(x1, w1[128 + j], a);
                a = fmaf(x2, w1[256 + j], a);
                a = fmaf(x3, w1[384 + j], a);
                h[e] = fmaxf(a, 0.0f);
            }
            u32x4 pk = { pkbf(h[0], h[1]), pkbf(h[2], h[3]),
                         pkbf(h[4], h[5]), pkbf(h[6], h[7]) };
            int a = (((px << 8) | (jc << 4))) ^ ((px & 15) << 4);
            *(u32x4*)(lds + a) = pk;
        }
    }
    __syncthreads();

    // ---- phase 2: all 128 px x this wave's 32 j, per-mt fused epilogue ----
#pragma unroll
    for (int mt = 0; mt < 8; ++mt) {
        short8 af[4];
#pragma unroll
        for (int ks = 0; ks < 4; ++ks) {
            int row = mt * 16 + lr16;
            int a = (((row << 8) | (ks << 6) | (lh << 4))) ^ ((row & 15) << 4);
            af[ks] = *(const short8*)(lds + a);
        }
        f32x4 a0 = (f32x4){b2v[0], b2v[0], b2v[0], b2v[0]};
        f32x4 a1 = (f32x4){b2v[1], b2v[1], b2v[1], b2v[1]};
#pragma unroll
        for (int ks = 0; ks < 4; ++ks) {
            a0 = __builtin_amdgcn_mfma_f32_16x16x32_bf16(af[ks], bf[0][ks], a0, 0, 0, 0);
            a1 = __builtin_amdgcn_mfma_f32_16x16x32_bf16(af[ks], bf[1][ks], a1, 0, 0, 0);
        }
#pragma unroll
        for (int r = 0; r < 4; ++r) {
            float part = fmaxf(a0[r], 0.f) * w3v[0] + fmaxf(a1[r], 0.f) * w3v[1];
            part += __shfl_xor(part, 1);
            part += __shfl_xor(part, 2);
            part += __shfl_xor(part, 4);
            part += __shfl_xor(part, 8);
            if (lr16 == 0) part_l[w][mt * 16 + lh * 4 + r] = part;  // row=(lane>>4)*4+r
        }
    }
    __syncthreads();

    // ---- combine: 128 threads sum 4 wave-partials, sigmoid, select ----
    if (t < 128) {
        float s = b3v + part_l[0][t] + part_l[1][t] + part_l[2][t] + part_l[3][t];
        out[p] = sel ? (1.0f / (1.0f + __expf(-s))) : lrv;
    }
}

// ---------------- launcher ----------------------------------------------------
extern "C" void kernel_launch(void* const* d_in, const int* in_sizes, int n_in,
                              void* d_out, int out_size, void* d_ws, size_t ws_size,
                              hipStream_t stream) {
    const float* image = (const float*)d_in[0];
    const float* lr    = (const float*)d_in[1];
    const float* w1    = (const float*)d_in[2];
    const float* b1    = (const float*)d_in[3];
    const float* w2    = (const float*)d_in[4];
    const float* b2    = (const float*)d_in[5];
    const float* w3    = (const float*)d_in[6];
    const float* b3    = (const float*)d_in[7];
    float* out = (float*)d_out;

    char* ws = (char*)d_ws;
    unsigned char* rowdil = (unsigned char*)ws;                         // NPIX
    unsigned char* dm     = (unsigned char*)(ws + (size_t)NPIX);        // NPIX
    unsigned char* rankb  = (unsigned char*)(ws + 2 * (size_t)NPIX);    // NPIX
    int* gsum             = (int*)(ws + 3 * (size_t)NPIX);              // NB
    int* goff             = (int*)(ws + 3 * (size_t)NPIX + NB * 4);     // NB
    unsigned short* w2f   = (unsigned short*)(ws + 3 * (size_t)NPIX + 2 * NB * 4); // 16384 bf16

    k_prep_w2<<<64, 256, 0, stream>>>(w2, w2f);
    k_rowdil <<<NPIX / 256, 256, 0, stream>>>(lr, rowdil);
    k_coldil <<<NB, 256, 0, stream>>>(rowdil, dm, rankb, gsum);
    k_scan   <<<1, 1024, 0, stream>>>(gsum, goff);
    k_mlp    <<<NMLP, 256, 0, stream>>>(image, lr, w1, b1, w2f, b2, w3, b3,
                                        dm, rankb, goff, out);
}